// Round 3
// baseline (204.577 us; speedup 1.0000x reference)
//
#include <hip/hip_runtime.h>
#include <math.h>

#define BT     1024
#define NWAVE  16
#define NROW   100
#define DDIM   768
#define NPACK  384          // DDIM/2 packed bf16 pairs per row
#define EPS_LN 1e-5f
#define EPSF   1e-8f

// LDS layout (bytes), total 160948 <= 163840:
//   u     : [100][384] uint (bf16 pairs) -> 153600 @ 0
//   S     : [768] float                  ->   3072 @ 153600
//   shift : [768] float                  ->   3072 @ 156672
//   nrm   : [100] float                  ->    400 @ 159744
//   dens  : [100] float                  ->    400 @ 160144
//   w2    : [100] float                  ->    400 @ 160544
//   Wsh   : [1] float                    ->      4 @ 160944
#define LDS_BYTES 160948

__device__ __forceinline__ unsigned int f2bf1(float f) {
    union { float f; unsigned int u; } c; c.f = f;
    return (c.u + 0x7FFFu + ((c.u >> 16) & 1u)) >> 16;
}
__device__ __forceinline__ unsigned int packbf(float lo, float hi) {
    return f2bf1(lo) | (f2bf1(hi) << 16);
}
__device__ __forceinline__ float bflo(unsigned int p) {
    union { unsigned int u; float f; } c; c.u = p << 16; return c.f;
}
__device__ __forceinline__ float bfhi(unsigned int p) {
    union { unsigned int u; float f; } c; c.u = p & 0xFFFF0000u; return c.f;
}
__device__ __forceinline__ float wave_sum(float v) {
#pragma unroll
    for (int m = 32; m >= 1; m >>= 1) v += __shfl_xor(v, m, 64);
    return v;
}

extern "C" __global__ void __launch_bounds__(BT, 4)
ccs_kernel(const float* __restrict__ x,
           const float* __restrict__ cc,
           const float* __restrict__ alpha,
           const float* __restrict__ gamma,
           const float* __restrict__ beta,
           const float* __restrict__ thw,
           const float* __restrict__ thb,
           float* __restrict__ out)
{
    extern __shared__ char lds[];
    unsigned int* u = (unsigned int*)lds;              // [100][384]
    float* S     = (float*)(lds + 153600);
    float* shift = (float*)(lds + 156672);
    float* nrm   = (float*)(lds + 159744);
    float* dens  = (float*)(lds + 160144);
    float* w2    = (float*)(lds + 160544);
    float* Wsh   = (float*)(lds + 160944);

    const int tid = threadIdx.x;
    const int w   = tid >> 6;
    const int l   = tid & 63;
    const int b   = blockIdx.x;
    const float* xb = x + (size_t)b * (NROW * DDIM);

    // zero the two column-reduction accumulators
    if (tid < DDIM) { S[tid] = 0.f; shift[tid] = 0.f; }
    __syncthreads();

    // gamma/beta: load once, reuse for all rows (lane covers d = k*256 + 4l + i)
    float gf[12], bfv[12];
#pragma unroll
    for (int k = 0; k < 3; ++k) {
        *(float4*)&gf[4 * k]  = *(const float4*)(gamma + k * 256 + 4 * l);
        *(float4*)&bfv[4 * k] = *(const float4*)(beta  + k * 256 + 4 * l);
    }

    // ---------- Pass 1: stream x, LayerNorm, L2-normalize, u -> LDS (bf16) ----------
    float Sl[12];
#pragma unroll
    for (int m = 0; m < 12; ++m) Sl[m] = 0.f;

    for (int n = w; n < NROW; n += NWAVE) {
        const float* xr = xb + n * DDIM;
        float xf[12];
        *(float4*)&xf[0] = *(const float4*)(xr +   0 + 4 * l);
        *(float4*)&xf[4] = *(const float4*)(xr + 256 + 4 * l);
        *(float4*)&xf[8] = *(const float4*)(xr + 512 + 4 * l);

        float s = 0.f, sq = 0.f;
#pragma unroll
        for (int m = 0; m < 12; ++m) { s += xf[m]; sq += xf[m] * xf[m]; }
#pragma unroll
        for (int msk = 32; msk >= 1; msk >>= 1) {
            s  += __shfl_xor(s,  msk, 64);
            sq += __shfl_xor(sq, msk, 64);
        }
        const float mu   = s * (1.0f / DDIM);
        const float var  = sq * (1.0f / DDIM) - mu * mu;
        const float rstd = rsqrtf(var + EPS_LN);

        float q = 0.f;
#pragma unroll
        for (int m = 0; m < 12; ++m) {
            const float v = (xf[m] - mu) * rstd * gf[m] + bfv[m];
            xf[m] = v;
            q += v * v;
        }
        q = wave_sum(q);
        const float nr  = sqrtf(q);
        const float inv = (nr > 0.f) ? (1.0f / nr) : 0.f;
#pragma unroll
        for (int m = 0; m < 12; ++m) { xf[m] *= inv; Sl[m] += xf[m]; }

        unsigned int* ur = u + n * NPACK;
#pragma unroll
        for (int k = 0; k < 3; ++k) {
            uint2 p;
            p.x = packbf(xf[4 * k + 0], xf[4 * k + 1]);
            p.y = packbf(xf[4 * k + 2], xf[4 * k + 3]);
            *(uint2*)&ur[k * 128 + 2 * l] = p;
        }
        if (l == 0) nrm[n] = nr;
    }

    // cross-wave column sum S[d] += Sl  (12 ds_add_f32 per lane)
#pragma unroll
    for (int m = 0; m < 12; ++m)
        atomicAdd(&S[(m >> 2) * 256 + 4 * l + (m & 3)], Sl[m]);
    __syncthreads();

    // ---------- Pass 2a: density[n] = u_n . S ----------
    float Sv[12];
#pragma unroll
    for (int k = 0; k < 3; ++k)
        *(float4*)&Sv[4 * k] = *(const float4*)&S[k * 256 + 4 * l];

    for (int n = w; n < NROW; n += NWAVE) {
        const unsigned int* ur = u + n * NPACK;
        float dot = 0.f;
#pragma unroll
        for (int k = 0; k < 3; ++k) {
            const uint2 p = *(const uint2*)&ur[k * 128 + 2 * l];
            dot += bflo(p.x) * Sv[4 * k + 0] + bfhi(p.x) * Sv[4 * k + 1]
                 + bflo(p.y) * Sv[4 * k + 2] + bfhi(p.y) * Sv[4 * k + 3];
        }
        dot = wave_sum(dot);
        if (l == 0) dens[n] = dot;
    }
    __syncthreads();

    // ---------- Pass 2b: min-max normalize, sigmoid threshold, gate (wave 0) ----------
    if (w == 0) {
        const float va = dens[l];
        const bool  hb = (l < NROW - 64);
        const float vb = hb ? dens[64 + l] : 0.f;

        float mxv = hb ? fmaxf(va, vb) : va;
        float mnv = hb ? fminf(va, vb) : va;
#pragma unroll
        for (int m = 32; m >= 1; m >>= 1) {
            mxv = fmaxf(mxv, __shfl_xor(mxv, m, 64));
            mnv = fminf(mnv, __shfl_xor(mnv, m, 64));
        }
        const float rng = 1.0f / (mxv - mnv + EPSF);
        const float ra  = (va - mnv) * rng;
        const float rb  = (vb - mnv) * rng;

        float td = ra * thw[l] + (hb ? rb * thw[64 + l] : 0.f);
        td = wave_sum(td);
        const float z  = td + thb[0];
        const float th = alpha[0] / (1.0f + expf(-z));

        const float ga = fmaxf(ra - th, 0.f);
        const float gb = hb ? fmaxf(rb - th, 0.f) : 0.f;
        const float sg = wave_sum(ga + gb);
        const float wf = 1.0f / (sg + EPSF);

        w2[l] = ga * wf * nrm[l];
        if (hb) w2[64 + l] = gb * wf * nrm[64 + l];
        if (l == 0) Wsh[0] = sg * wf;
    }
    __syncthreads();

    // ---------- Pass 3: shift[d] = sum_n w2[n]*u[n][d] (wave-local rows + atomics) ----------
    float acc[12];
#pragma unroll
    for (int m = 0; m < 12; ++m) acc[m] = 0.f;

    for (int n = w; n < NROW; n += NWAVE) {
        const unsigned int* ur = u + n * NPACK;
        const float wv = w2[n];
#pragma unroll
        for (int k = 0; k < 3; ++k) {
            const uint2 p = *(const uint2*)&ur[k * 128 + 2 * l];
            acc[4 * k + 0] += wv * bflo(p.x);
            acc[4 * k + 1] += wv * bfhi(p.x);
            acc[4 * k + 2] += wv * bflo(p.y);
            acc[4 * k + 3] += wv * bfhi(p.y);
        }
    }
#pragma unroll
    for (int m = 0; m < 12; ++m)
        atomicAdd(&shift[(m >> 2) * 256 + 4 * l + (m & 3)], acc[m]);
    __syncthreads();

    // ---------- Output ----------
    if (tid < DDIM) {
        const float a = shift[tid];
        const float c = cc[(size_t)b * DDIM + tid];
        out[(size_t)b * DDIM + tid] = c + (a - c * Wsh[0]) * (1.0f / NROW);
    }
}

extern "C" void kernel_launch(void* const* d_in, const int* in_sizes, int n_in,
                              void* d_out, int out_size, void* d_ws, size_t ws_size,
                              hipStream_t stream) {
    const float* x     = (const float*)d_in[0];
    const float* cc    = (const float*)d_in[1];
    const float* alpha = (const float*)d_in[2];
    const float* gamma = (const float*)d_in[3];
    const float* beta  = (const float*)d_in[4];
    const float* thw   = (const float*)d_in[5];
    const float* thb   = (const float*)d_in[6];
    float* out = (float*)d_out;

    ccs_kernel<<<1024, BT, LDS_BYTES, stream>>>(x, cc, alpha, gamma, beta, thw, thb, out);
}

// Round 4
// 102.670 us; speedup vs baseline: 1.9926x; 1.9926x over previous
//
#include <hip/hip_runtime.h>
#include <math.h>

#define BT     1024
#define NWAVE  16
#define NROW   100
#define DDIM   768
#define EPS_LN 1e-5f
#define EPSF   1e-8f

// LDS layout (bytes), total 157876:
//   u    : [100][384] uint (bf16 pairs, word j <-> cols 2j,2j+1) @ 0      (153600)
//   S    : [768] float   @ 153600
//   nrm  : [100] float   @ 156672
//   dens : [100] float   @ 157072
//   w2   : [100] float   @ 157472
//   Wsh  : [1]  float    @ 157872
#define LDS_BYTES 157876

__device__ __forceinline__ unsigned int f2bf1(float f) {
    union { float f; unsigned int u; } c; c.f = f;
    return (c.u + 0x7FFFu + ((c.u >> 16) & 1u)) >> 16;
}
__device__ __forceinline__ unsigned int packbf(float lo, float hi) {
    return f2bf1(lo) | (f2bf1(hi) << 16);
}
__device__ __forceinline__ float bflo(unsigned int p) {
    union { unsigned int u; float f; } c; c.u = p << 16; return c.f;
}
__device__ __forceinline__ float bfhi(unsigned int p) {
    union { unsigned int u; float f; } c; c.u = p & 0xFFFF0000u; return c.f;
}
__device__ __forceinline__ float wave_sum(float v) {
#pragma unroll
    for (int m = 32; m >= 1; m >>= 1) v += __shfl_xor(v, m, 64);
    return v;
}

extern "C" __global__ void __launch_bounds__(BT, 4)
ccs_kernel(const float* __restrict__ x,
           const float* __restrict__ cc,
           const float* __restrict__ alpha,
           const float* __restrict__ gamma,
           const float* __restrict__ beta,
           const float* __restrict__ thw,
           const float* __restrict__ thb,
           float* __restrict__ out)
{
    extern __shared__ char lds[];
    unsigned int* u = (unsigned int*)lds;          // [100][384]
    float* S    = (float*)(lds + 153600);
    float* nrm  = (float*)(lds + 156672);
    float* dens = (float*)(lds + 157072);
    float* w2   = (float*)(lds + 157472);
    float* Wsh  = (float*)(lds + 157872);

    const int tid = threadIdx.x;
    const int w   = tid >> 6;
    const int l   = tid & 63;
    const int b   = blockIdx.x;
    const float* xb = x + (size_t)b * (NROW * DDIM);

    // ---- hoisted small global loads (latency hidden under pass 1) ----
    float thwa = 0.f, thwb = 0.f, alphav = 0.f, thbv = 0.f;
    if (w == 0) {
        thwa = thw[l];
        if (l < NROW - 64) thwb = thw[64 + l];
        alphav = alpha[0];
        thbv   = thb[0];
    }
    float2 ccv = make_float2(0.f, 0.f);
    if (tid < 384) ccv = *(const float2*)(cc + (size_t)b * DDIM + 2 * tid);

    // gamma/beta (lane covers cols d = k*256 + 4l + i)
    float gf[12], bv[12];
#pragma unroll
    for (int k = 0; k < 3; ++k) {
        *(float4*)&gf[4 * k] = *(const float4*)(gamma + k * 256 + 4 * l);
        *(float4*)&bv[4 * k] = *(const float4*)(beta  + k * 256 + 4 * l);
    }

    // per-block constants: Σβ², Σγβ, Σγ²  (single 6-step chain)
    float c_b2 = 0.f, c_gb = 0.f, c_g2 = 0.f;
#pragma unroll
    for (int m = 0; m < 12; ++m) {
        c_b2 += bv[m] * bv[m];
        c_gb += gf[m] * bv[m];
        c_g2 += gf[m] * gf[m];
    }
#pragma unroll
    for (int msk = 32; msk >= 1; msk >>= 1) {
        c_b2 += __shfl_xor(c_b2, msk, 64);
        c_gb += __shfl_xor(c_gb, msk, 64);
        c_g2 += __shfl_xor(c_g2, msk, 64);
    }

    // ---------- Pass 1: stream x, fused LN+L2norm stats, u -> LDS bf16 ----------
    const int cnt = (w < 4) ? 7 : 6;    // rows n = w + 16r
    float xf[12];
    {
        const float* xr = xb + w * DDIM;
        *(float4*)&xf[0] = *(const float4*)(xr +   0 + 4 * l);
        *(float4*)&xf[4] = *(const float4*)(xr + 256 + 4 * l);
        *(float4*)&xf[8] = *(const float4*)(xr + 512 + 4 * l);
    }
    for (int r = 0; r < cnt; ++r) {
        const int n = w + 16 * r;
        float xn1[12];
        if (r + 1 < cnt) {              // prefetch next row before the chain
            const float* xr = xb + (n + 16) * DDIM;
            *(float4*)&xn1[0] = *(const float4*)(xr +   0 + 4 * l);
            *(float4*)&xn1[4] = *(const float4*)(xr + 256 + 4 * l);
            *(float4*)&xn1[8] = *(const float4*)(xr + 512 + 4 * l);
        }

        // 5 simultaneous partials: Σx, Σx², Σ(γx)², Σγ(γx), Σβ(γx)
        float p0 = 0.f, p1 = 0.f, p2 = 0.f, p3 = 0.f, p4 = 0.f;
#pragma unroll
        for (int m = 0; m < 12; ++m) {
            const float xv = xf[m];
            const float t  = gf[m] * xv;
            p0 += xv; p1 += xv * xv;
            p2 += t * t; p3 += gf[m] * t; p4 += bv[m] * t;
        }
#pragma unroll
        for (int msk = 32; msk >= 1; msk >>= 1) {
            p0 += __shfl_xor(p0, msk, 64);
            p1 += __shfl_xor(p1, msk, 64);
            p2 += __shfl_xor(p2, msk, 64);
            p3 += __shfl_xor(p3, msk, 64);
            p4 += __shfl_xor(p4, msk, 64);
        }
        const float mu  = p0 * (1.0f / DDIM);
        const float var = p1 * (1.0f / DDIM) - mu * mu;
        const float A   = rsqrtf(var + EPS_LN);
        // q = ||xn||² = A²Σ(γx)² + 2A·Σγx·B + ΣB²,  B_d = β_d − A·mu·γ_d
        const float q   = A * A * p2 + 2.f * A * (p4 - A * mu * p3)
                        + (c_b2 - 2.f * A * mu * c_gb + A * A * mu * mu * c_g2);
        const float qc  = fmaxf(q, 1e-30f);
        const float inv = rsqrtf(qc);
        const float nr  = qc * inv;     // sqrt(q)
        const float c1  = inv * A;

        unsigned int* ur = u + n * 384;
#pragma unroll
        for (int k = 0; k < 3; ++k) {
            const float u0 = c1 * gf[4*k+0] * (xf[4*k+0] - mu) + inv * bv[4*k+0];
            const float u1 = c1 * gf[4*k+1] * (xf[4*k+1] - mu) + inv * bv[4*k+1];
            const float u2 = c1 * gf[4*k+2] * (xf[4*k+2] - mu) + inv * bv[4*k+2];
            const float u3 = c1 * gf[4*k+3] * (xf[4*k+3] - mu) + inv * bv[4*k+3];
            uint2 p;
            p.x = packbf(u0, u1);
            p.y = packbf(u2, u3);
            *(uint2*)&ur[k * 128 + 2 * l] = p;
        }
        if (l == 0) nrm[n] = nr;

        if (r + 1 < cnt) {
#pragma unroll
            for (int m = 0; m < 12; ++m) xf[m] = xn1[m];
        }
    }
    __syncthreads();

    // ---------- Pass S: columnwise S[d] = Σ_n u[n][d]  (384 threads, word t = cols 2t,2t+1) ----------
    if (tid < 384) {
        float ax = 0.f, ay = 0.f;
        const unsigned int* up = u + tid;
#pragma unroll 4
        for (int n = 0; n < NROW; ++n) {
            const unsigned int pw = up[n * 384];
            ax += bflo(pw); ay += bfhi(pw);
        }
        *(float2*)&S[2 * tid] = make_float2(ax, ay);
    }
    __syncthreads();

    // ---------- Pass 2a: density[n] = u_n · S  (7 dots per wave, ONE shared chain) ----------
    float Sv[12];
#pragma unroll
    for (int k = 0; k < 3; ++k)
        *(float4*)&Sv[4 * k] = *(const float4*)&S[k * 256 + 4 * l];

    float dot[7];
#pragma unroll
    for (int r = 0; r < 7; ++r) dot[r] = 0.f;
#pragma unroll
    for (int r = 0; r < 7; ++r) {
        if (r < cnt) {
            const unsigned int* ur = u + (w + 16 * r) * 384;
            float d = 0.f;
#pragma unroll
            for (int k = 0; k < 3; ++k) {
                const uint2 p = *(const uint2*)&ur[k * 128 + 2 * l];
                d += bflo(p.x) * Sv[4*k+0] + bfhi(p.x) * Sv[4*k+1]
                   + bflo(p.y) * Sv[4*k+2] + bfhi(p.y) * Sv[4*k+3];
            }
            dot[r] = d;
        }
    }
#pragma unroll
    for (int msk = 32; msk >= 1; msk >>= 1) {
#pragma unroll
        for (int r = 0; r < 7; ++r) dot[r] += __shfl_xor(dot[r], msk, 64);
    }
    if (l == 0) {
#pragma unroll
        for (int r = 0; r < 7; ++r)
            if (r < cnt) dens[w + 16 * r] = dot[r];
    }
    __syncthreads();

    // ---------- Pass 2b: min-max normalize, sigmoid threshold, gate (wave 0) ----------
    if (w == 0) {
        const float va = dens[l];
        const bool  hb = (l < NROW - 64);
        const float vb = hb ? dens[64 + l] : 0.f;

        float mxv = hb ? fmaxf(va, vb) : va;
        float mnv = hb ? fminf(va, vb) : va;
#pragma unroll
        for (int m = 32; m >= 1; m >>= 1) {
            mxv = fmaxf(mxv, __shfl_xor(mxv, m, 64));
            mnv = fminf(mnv, __shfl_xor(mnv, m, 64));
        }
        const float rng = 1.0f / (mxv - mnv + EPSF);
        const float ra  = (va - mnv) * rng;
        const float rb  = (vb - mnv) * rng;

        float td = ra * thwa + (hb ? rb * thwb : 0.f);
        td = wave_sum(td);
        const float z  = td + thbv;
        const float th = alphav / (1.0f + expf(-z));

        const float ga  = fmaxf(ra - th, 0.f);
        const float gb_ = hb ? fmaxf(rb - th, 0.f) : 0.f;
        const float sg  = wave_sum(ga + gb_);
        const float wf  = 1.0f / (sg + EPSF);

        w2[l] = ga * wf * nrm[l];
        if (hb) w2[64 + l] = gb_ * wf * nrm[64 + l];
        if (l == 0) Wsh[0] = sg * wf;
    }
    __syncthreads();

    // ---------- Pass 3 + output: out[d] = cc + (Σ_n w2[n]u[n][d] − cc·W)/N ----------
    if (tid < 384) {
        float ax = 0.f, ay = 0.f;
        const unsigned int* up = u + tid;
#pragma unroll 4
        for (int n = 0; n < NROW; ++n) {
            const float wv = w2[n];
            const unsigned int pw = up[n * 384];
            ax += wv * bflo(pw); ay += wv * bfhi(pw);
        }
        const float W = Wsh[0];
        float2 o;
        o.x = ccv.x + (ax - ccv.x * W) * (1.0f / NROW);
        o.y = ccv.y + (ay - ccv.y * W) * (1.0f / NROW);
        *(float2*)(out + (size_t)b * DDIM + 2 * tid) = o;
    }
}

extern "C" void kernel_launch(void* const* d_in, const int* in_sizes, int n_in,
                              void* d_out, int out_size, void* d_ws, size_t ws_size,
                              hipStream_t stream) {
    const float* x     = (const float*)d_in[0];
    const float* cc    = (const float*)d_in[1];
    const float* alpha = (const float*)d_in[2];
    const float* gamma = (const float*)d_in[3];
    const float* beta  = (const float*)d_in[4];
    const float* thw   = (const float*)d_in[5];
    const float* thb   = (const float*)d_in[6];
    float* out = (float*)d_out;

    ccs_kernel<<<1024, BT, LDS_BYTES, stream>>>(x, cc, alpha, gamma, beta, thw, thb, out);
}

// Round 5
// 88.467 us; speedup vs baseline: 2.3125x; 1.1605x over previous
//
#include <hip/hip_runtime.h>
#include <math.h>

#define BT     1024
#define NROW   100
#define DDIM   768
#define EPS_LN 1e-5f
#define EPSF   1e-8f

// LDS layout (bytes), total 160144 <= 163840:
//   u      : [100][384] uint (bf16 pairs; word j <-> cols 2j,2j+1) @ 0  (153600)
//   dual region @153600 (6144):
//     pass-1 : gammaL[768] f32 @153600, betaL[768] f32 @156672
//     after  : S[768] f32 @153600, dens[100] @156672, w2[100] @157072, Wsh @157472
//   nrm    : [100] f32 @159744
#define LDS_BYTES 160144

__device__ __forceinline__ float bflo(unsigned int p) {
    union { unsigned int u; float f; } c; c.u = p << 16; return c.f;
}
__device__ __forceinline__ float bfhi(unsigned int p) {
    union { unsigned int u; float f; } c; c.u = p & 0xFFFF0000u; return c.f;
}
__device__ __forceinline__ unsigned int cvtpk(float lo, float hi) {
    unsigned int r;
    asm("v_cvt_pk_bf16_f32 %0, %1, %2" : "=v"(r) : "v"(lo), "v"(hi));
    return r;   // lo -> bits [15:0], hi -> bits [31:16], RNE
}
__device__ __forceinline__ float wave_sum(float v) {
#pragma unroll
    for (int m = 32; m >= 1; m >>= 1) v += __shfl_xor(v, m, 64);
    return v;
}
__device__ __forceinline__ float half_sum(float v) {   // reduce within 32-lane half
#pragma unroll
    for (int m = 16; m >= 1; m >>= 1) v += __shfl_xor(v, m, 64);
    return v;
}

extern "C" __global__ void __launch_bounds__(BT, 4)
ccs_kernel(const float* __restrict__ x,
           const float* __restrict__ cc,
           const float* __restrict__ alpha,
           const float* __restrict__ gamma,
           const float* __restrict__ beta,
           const float* __restrict__ thw,
           const float* __restrict__ thb,
           float* __restrict__ out)
{
    extern __shared__ char lds[];
    unsigned int* u = (unsigned int*)lds;              // [100][384]
    float* gammaL = (float*)(lds + 153600);            // pass-1 only
    float* betaL  = (float*)(lds + 156672);            // pass-1 only
    float* S      = (float*)(lds + 153600);            // post-pass-1
    float* dens   = (float*)(lds + 156672);
    float* w2     = (float*)(lds + 157072);
    float* Wsh    = (float*)(lds + 157472);
    float* nrm    = (float*)(lds + 159744);

    const int tid = threadIdx.x;
    const int w   = tid >> 6;
    const int l   = tid & 63;
    const int li  = l & 31;          // lane within half-wave
    const int hw  = (w << 1) | (l >> 5);   // half-wave id 0..31
    const int b   = blockIdx.x;
    const float* xb = x + (size_t)b * (NROW * DDIM);

    // ---- hoisted small global loads ----
    float thwa = 0.f, thwb = 0.f, alphav = 0.f, thbv = 0.f;
    if (w == 0) {
        thwa = thw[l];
        if (l < NROW - 64) thwb = thw[64 + l];
        alphav = alpha[0];
        thbv   = thb[0];
    }
    float2 ccv = make_float2(0.f, 0.f);
    if (tid < 384) ccv = *(const float2*)(cc + (size_t)b * DDIM + 2 * tid);

    // ---- issue first row's loads immediately (row = hw, cols 4*li + 128k) ----
    const int base  = 4 * li;
    const int pcnt  = (hw < 4) ? 4 : 3;     // rows n = hw + 32r; 100 = 4*4 + 28*3... (hw<4: 4 rows)
    float xf[24];
    {
        const float* xr = xb + hw * DDIM + base;
#pragma unroll
        for (int k = 0; k < 6; ++k)
            *(float4*)&xf[4 * k] = *(const float4*)(xr + 128 * k);
    }

    // ---- stage gamma/beta into LDS (overlaps with xf loads in flight) ----
    if (tid < DDIM) { gammaL[tid] = gamma[tid]; betaL[tid] = beta[tid]; }
    __syncthreads();

    // ---------- Pass 1: half-wave per row ----------
#pragma unroll
    for (int r = 0; r < 4; ++r) {
        if (r >= pcnt) break;
        const int row = hw + 32 * r;

        // stats over this lane's 24 elements
        float p0 = 0.f, p1 = 0.f;
#pragma unroll
        for (int m = 0; m < 24; ++m) { p0 += xf[m]; p1 += xf[m] * xf[m]; }

        // prefetch next row before the reduce chain
        float xn1[24];
        if (r + 1 < pcnt) {
            const float* xr = xb + (row + 32) * DDIM + base;
#pragma unroll
            for (int k = 0; k < 6; ++k)
                *(float4*)&xn1[4 * k] = *(const float4*)(xr + 128 * k);
        }

#pragma unroll
        for (int m = 16; m >= 1; m >>= 1) {
            p0 += __shfl_xor(p0, m, 64);
            p1 += __shfl_xor(p1, m, 64);
        }
        const float mu  = p0 * (1.0f / DDIM);
        const float var = p1 * (1.0f / DDIM) - mu * mu;
        const float A   = rsqrtf(var + EPS_LN);
        const float nmuA = -mu * A;

        // xn in place (xf <- A*(x-mu)*gamma + beta), accumulate q = ||xn||^2
        float q = 0.f;
#pragma unroll
        for (int k = 0; k < 6; ++k) {
            const float4 g4 = *(const float4*)&gammaL[base + 128 * k];
            const float4 b4 = *(const float4*)&betaL [base + 128 * k];
            const float* gp = (const float*)&g4;
            const float* bp = (const float*)&b4;
#pragma unroll
            for (int i = 0; i < 4; ++i) {
                const float t = fmaf(xf[4 * k + i], A, nmuA);
                const float v = fmaf(t, gp[i], bp[i]);
                xf[4 * k + i] = v;
                q += v * v;
            }
        }
        q = half_sum(q);
        const float qc  = fmaxf(q, 1e-30f);
        const float inv = rsqrtf(qc);
        const float nr  = qc * inv;    // sqrt(q)

        // pack u = xn * inv -> bf16 pairs; lane owns words 2*li + 64k (+1)
        unsigned int* ur = u + row * 384 + 2 * li;
#pragma unroll
        for (int k = 0; k < 6; ++k) {
            uint2 pk;
            pk.x = cvtpk(xf[4 * k + 0] * inv, xf[4 * k + 1] * inv);
            pk.y = cvtpk(xf[4 * k + 2] * inv, xf[4 * k + 3] * inv);
            *(uint2*)&ur[64 * k] = pk;
        }
        if (li == 0) nrm[row] = nr;

        if (r + 1 < pcnt) {
#pragma unroll
            for (int m = 0; m < 24; ++m) xf[m] = xn1[m];
        }
    }
    __syncthreads();

    // ---------- Pass S: S[d] = sum_n u[n][d] (384 threads, word t = cols 2t,2t+1) ----------
    if (tid < 384) {
        float ax = 0.f, ay = 0.f;
        const unsigned int* up = u + tid;
#pragma unroll 4
        for (int n = 0; n < NROW; ++n) {
            const unsigned int pw = up[n * 384];
            ax += bflo(pw); ay += bfhi(pw);
        }
        *(float2*)&S[2 * tid] = make_float2(ax, ay);
    }
    __syncthreads();

    // ---------- Pass 2a: density[n] = u_n . S (full-wave rows, batched chain) ----------
    const int cnt = (w < 4) ? 7 : 6;    // rows n = w + 16r
    float Sv[12];
#pragma unroll
    for (int k = 0; k < 3; ++k)
        *(float4*)&Sv[4 * k] = *(const float4*)&S[k * 256 + 4 * l];

    float dot[7];
#pragma unroll
    for (int r = 0; r < 7; ++r) dot[r] = 0.f;
#pragma unroll
    for (int r = 0; r < 7; ++r) {
        if (r < cnt) {
            const unsigned int* ur = u + (w + 16 * r) * 384;
            float d = 0.f;
#pragma unroll
            for (int k = 0; k < 3; ++k) {
                const uint2 p = *(const uint2*)&ur[k * 128 + 2 * l];
                d += bflo(p.x) * Sv[4*k+0] + bfhi(p.x) * Sv[4*k+1]
                   + bflo(p.y) * Sv[4*k+2] + bfhi(p.y) * Sv[4*k+3];
            }
            dot[r] = d;
        }
    }
#pragma unroll
    for (int msk = 32; msk >= 1; msk >>= 1) {
#pragma unroll
        for (int r = 0; r < 7; ++r) dot[r] += __shfl_xor(dot[r], msk, 64);
    }
    if (l == 0) {
#pragma unroll
        for (int r = 0; r < 7; ++r)
            if (r < cnt) dens[w + 16 * r] = dot[r];
    }
    __syncthreads();

    // ---------- Pass 2b: min-max normalize, sigmoid threshold, gate (wave 0) ----------
    if (w == 0) {
        const float va = dens[l];
        const bool  hb = (l < NROW - 64);
        const float vb = hb ? dens[64 + l] : 0.f;

        float mxv = hb ? fmaxf(va, vb) : va;
        float mnv = hb ? fminf(va, vb) : va;
#pragma unroll
        for (int m = 32; m >= 1; m >>= 1) {
            mxv = fmaxf(mxv, __shfl_xor(mxv, m, 64));
            mnv = fminf(mnv, __shfl_xor(mnv, m, 64));
        }
        const float rng = 1.0f / (mxv - mnv + EPSF);
        const float ra  = (va - mnv) * rng;
        const float rb  = (vb - mnv) * rng;

        float td = ra * thwa + (hb ? rb * thwb : 0.f);
        td = wave_sum(td);
        const float z  = td + thbv;
        const float th = alphav / (1.0f + expf(-z));

        const float ga  = fmaxf(ra - th, 0.f);
        const float gb_ = hb ? fmaxf(rb - th, 0.f) : 0.f;
        const float sg  = wave_sum(ga + gb_);
        const float wf  = 1.0f / (sg + EPSF);

        w2[l] = ga * wf * nrm[l];
        if (hb) w2[64 + l] = gb_ * wf * nrm[64 + l];
        if (l == 0) Wsh[0] = sg * wf;
    }
    __syncthreads();

    // ---------- Pass 3 + output ----------
    if (tid < 384) {
        float ax = 0.f, ay = 0.f;
        const unsigned int* up = u + tid;
#pragma unroll 4
        for (int n = 0; n < NROW; ++n) {
            const float wv = w2[n];
            const unsigned int pw = up[n * 384];
            ax += wv * bflo(pw); ay += wv * bfhi(pw);
        }
        const float W = Wsh[0];
        float2 o;
        o.x = ccv.x + (ax - ccv.x * W) * (1.0f / NROW);
        o.y = ccv.y + (ay - ccv.y * W) * (1.0f / NROW);
        *(float2*)(out + (size_t)b * DDIM + 2 * tid) = o;
    }
}

extern "C" void kernel_launch(void* const* d_in, const int* in_sizes, int n_in,
                              void* d_out, int out_size, void* d_ws, size_t ws_size,
                              hipStream_t stream) {
    const float* x     = (const float*)d_in[0];
    const float* cc    = (const float*)d_in[1];
    const float* alpha = (const float*)d_in[2];
    const float* gamma = (const float*)d_in[3];
    const float* beta  = (const float*)d_in[4];
    const float* thw   = (const float*)d_in[5];
    const float* thb   = (const float*)d_in[6];
    float* out = (float*)d_out;

    ccs_kernel<<<1024, BT, LDS_BYTES, stream>>>(x, cc, alpha, gamma, beta, thw, thb, out);
}